// Round 2
// baseline (533.141 us; speedup 1.0000x reference)
//
#include <hip/hip_runtime.h>
#include <hip/hip_bf16.h>
#include <hip/hip_fp16.h>

// Pipeline (round 6 — fp16 gather payload + cache protection):
//   scatterA: bucket edges by dst>>7 into pairs[] (packed dl<<17|src),
//             LDS counting-sort -> wave-coalesced run writes
//   bucketB : per-bucket LDS sort -> dinv/row_start/row_end + csr (in-place)
//   xs(h16) = (x @ W1) * dinv[row]   (gemm1, K-split-4, nontemporal x reads)
//   gather1: hs(h16) = relu(dinv*(xs[self]+sum xs[csr]) + b1) * dinv
//   gather2: u = dinv*(hs[self]+sum hs[csr]); z = u@W2+b2; s1,s2 = z.We
//            (u broadcast via in-group shfl — no block barrier after staging)
//   logits (fused pos+neg) = s1[src] + s2[dst] + be
// Round 6 theory: gathers are payload/residency-bound (round-5 MLP fix
// saturated). fp16 xs/hs halves scattered bytes and makes the gather working
// set (3.2MB) L2-resident per XCD; nontemporal x stream stops gemm1 from
// evicting it. Accumulation order unchanged (fp32 math, fp16 storage only).

constexpr int TPB = 256;
constexpr int LOG_W = 7;
constexpr int W_BKT = 128;      // nodes per bucket
constexpr int NB_MAX = 1024;    // LDS array sizing (actual NB = 782)
constexpr int CAP = 5120;       // slots/bucket (mean 4096, sigma 64 -> +16s)
constexpr int EPB = 8192;       // edges per scatterA block

typedef float f4v __attribute__((ext_vector_type(4)));

__global__ __launch_bounds__(256) void scatterA_kernel(const int* __restrict__ src,
                                                       const int* __restrict__ dst,
                                                       int* __restrict__ bcursor,
                                                       int* __restrict__ pairs,
                                                       int E, int NB) {
    __shared__ int hist[NB_MAX];
    __shared__ int lstart[NB_MAX];
    __shared__ int gbase[NB_MAX];
    __shared__ int lcur[NB_MAX];
    __shared__ int csum[256];
    __shared__ int val[EPB];
    __shared__ unsigned short bkt[EPB];
    const int t = threadIdx.x;
    const int e0 = blockIdx.x * EPB;
    const int cnt = min(EPB, E - e0);

    for (int i = t; i < NB; i += 256) hist[i] = 0;
    __syncthreads();
    for (int i = t; i < cnt; i += 256) atomicAdd(&hist[dst[e0 + i] >> LOG_W], 1);
    __syncthreads();

    // exclusive scan of hist[0..NB) -> lstart (4 entries/thread + block scan)
    int loc[4], tsum = 0;
#pragma unroll
    for (int j = 0; j < 4; ++j) {
        int idx = t * 4 + j;
        int v = (idx < NB) ? hist[idx] : 0;
        loc[j] = tsum; tsum += v;
    }
    csum[t] = tsum;
    __syncthreads();
    for (int off = 1; off < 256; off <<= 1) {
        int v = (t >= off) ? csum[t - off] : 0;
        __syncthreads();
        csum[t] += v;
        __syncthreads();
    }
    int cbase = (t > 0) ? csum[t - 1] : 0;
#pragma unroll
    for (int j = 0; j < 4; ++j) {
        int idx = t * 4 + j;
        if (idx < NB) lstart[idx] = cbase + loc[j];
    }
    __syncthreads();
    // reserve global runs; init local cursors
    for (int b = t; b < NB; b += 256) {
        gbase[b] = hist[b] ? atomicAdd(&bcursor[b], hist[b]) : 0;
        lcur[b] = lstart[b];
    }
    __syncthreads();
    // counting-sort into LDS (re-read edges; coalesced, L3-hot)
    for (int i = t; i < cnt; i += 256) {
        int s = src[e0 + i], d = dst[e0 + i];
        int b = d >> LOG_W;
        int p = atomicAdd(&lcur[b], 1);
        val[p] = ((d & (W_BKT - 1)) << 17) | s;
        bkt[p] = (unsigned short)b;
    }
    __syncthreads();
    // coalesced copy-out of per-bucket runs
    for (int i = t; i < cnt; i += 256) {
        int b = bkt[i];
        int ofs = gbase[b] + (i - lstart[b]);
        if (ofs < CAP) pairs[(size_t)b * CAP + ofs] = val[i];
    }
}

// one block per bucket: counts -> dinv/row_start/row_end, LDS sort -> csr
__global__ __launch_bounds__(256) void bucketB_kernel(const int* __restrict__ bcursor,
                                                      int* __restrict__ pairs,  // in-place -> csr
                                                      float* __restrict__ dinv,
                                                      int* __restrict__ row_start,
                                                      int* __restrict__ row_end,
                                                      int N) {
    __shared__ int cnt[W_BKT];
    __shared__ int scn[W_BKT];
    __shared__ int cur[W_BKT];
    __shared__ int img[CAP];
    const int b = blockIdx.x;
    const int t = threadIdx.x;
    const int len = min(bcursor[b], CAP);
    const int n0 = b * W_BKT;
    int* p = pairs + (size_t)b * CAP;

    if (t < W_BKT) cnt[t] = 0;
    __syncthreads();
    for (int i = t; i < len; i += 256) atomicAdd(&cnt[p[i] >> 17], 1);
    __syncthreads();
    if (t < W_BKT) scn[t] = cnt[t];
    __syncthreads();
    for (int off = 1; off < W_BKT; off <<= 1) {
        int v = (t < W_BKT && t >= off) ? scn[t - off] : 0;
        __syncthreads();
        if (t < W_BKT) scn[t] += v;
        __syncthreads();
    }
    if (t < W_BKT) {
        int c = cnt[t];
        int es = scn[t] - c;          // exclusive start
        cur[t] = es;
        int n = n0 + t;
        if (n < N) {
            dinv[n] = rsqrtf((float)(c + 1));
            int rs = b * CAP + es;
            row_start[n] = rs;
            row_end[n] = rs + c;
        }
    }
    __syncthreads();
    for (int i = t; i < len; i += 256) {
        int v = p[i];
        int r = atomicAdd(&cur[v >> 17], 1);
        img[r] = v & 0x1FFFF;
    }
    __syncthreads();
    for (int i = t; i < len; i += 256) p[i] = img[i];
}

// xs = (x @ W1) * dinv[row], stored fp16.  K-split-4; nontemporal x reads
// (x is a 205MB one-shot stream — keep it from evicting xs/csr from L2/L3).
__global__ __launch_bounds__(256) void gemm1_kernel(const float* __restrict__ x,
                                                    const float* __restrict__ W1,
                                                    const float* __restrict__ dinv,
                                                    __half* __restrict__ xs, int N) {
    __shared__ float buf[512 * 16];  // W1 during compute, reduction after
    const int t = threadIdx.x;
    {
        const float4* w4 = (const float4*)W1;
        float4* b4 = (float4*)buf;
        for (int i = t; i < 2048; i += 256) b4[i] = w4[i];
    }
    __syncthreads();

    const int r = t & 63, q = t >> 6;
    const int row = blockIdx.x * 64 + r;
    const bool valid = row < N;
    const float* xrow = x + (size_t)row * 512 + q * 128;

    float acc[16];
#pragma unroll
    for (int c = 0; c < 16; ++c) acc[c] = 0.0f;

    if (valid) {
        const int kb = q * 128;
#pragma unroll 2
        for (int k0 = 0; k0 < 128; k0 += 16) {
            const f4v* xp = (const f4v*)(xrow + k0);
            f4v a0 = __builtin_nontemporal_load(xp);
            f4v a1 = __builtin_nontemporal_load(xp + 1);
            f4v a2 = __builtin_nontemporal_load(xp + 2);
            f4v a3 = __builtin_nontemporal_load(xp + 3);
            float xv[16] = {a0[0], a0[1], a0[2], a0[3], a1[0], a1[1], a1[2], a1[3],
                            a2[0], a2[1], a2[2], a2[3], a3[0], a3[1], a3[2], a3[3]};
#pragma unroll
            for (int kk = 0; kk < 16; ++kk) {
                const float4* wr = (const float4*)(buf + (kb + k0 + kk) * 16);
                float4 w0 = wr[0], w1 = wr[1], w2 = wr[2], w3 = wr[3];
                float xvk = xv[kk];
                acc[0]  += xvk * w0.x; acc[1]  += xvk * w0.y; acc[2]  += xvk * w0.z; acc[3]  += xvk * w0.w;
                acc[4]  += xvk * w1.x; acc[5]  += xvk * w1.y; acc[6]  += xvk * w1.z; acc[7]  += xvk * w1.w;
                acc[8]  += xvk * w2.x; acc[9]  += xvk * w2.y; acc[10] += xvk * w2.z; acc[11] += xvk * w2.w;
                acc[12] += xvk * w3.x; acc[13] += xvk * w3.y; acc[14] += xvk * w3.z; acc[15] += xvk * w3.w;
            }
        }
    }
    __syncthreads();

    float* red = buf;  // [3][64][16]
    if (q > 0) {
        float4* d0 = (float4*)(red + ((q - 1) * 64 + r) * 16);
        d0[0] = make_float4(acc[0], acc[1], acc[2], acc[3]);
        d0[1] = make_float4(acc[4], acc[5], acc[6], acc[7]);
        d0[2] = make_float4(acc[8], acc[9], acc[10], acc[11]);
        d0[3] = make_float4(acc[12], acc[13], acc[14], acc[15]);
    }
    __syncthreads();
    if (q == 0 && valid) {
#pragma unroll
        for (int p = 0; p < 3; ++p) {
            const float* sr = red + (p * 64 + r) * 16;
#pragma unroll
            for (int c = 0; c < 16; ++c) acc[c] += sr[c];
        }
        float di = dinv[row];
        __half hv[16];
#pragma unroll
        for (int c = 0; c < 16; ++c) hv[c] = __float2half_rn(acc[c] * di);
        float4* o = (float4*)(xs + (size_t)row * 16);   // 32B/row, 16B-aligned
        o[0] = *(const float4*)&hv[0];
        o[1] = *(const float4*)&hv[8];
    }
}

// hs[d] = relu(dinv[d]*(xs[d] + sum xs[csr]) + b1) * dinv[d]   (fp16 payload)
__global__ __launch_bounds__(256) void gather1_kernel(const __half* __restrict__ xs,
                                                      const int* __restrict__ csr,
                                                      const int* __restrict__ row_start,
                                                      const int* __restrict__ row_end,
                                                      const float* __restrict__ dinv,
                                                      const float* __restrict__ b1,
                                                      __half* __restrict__ hs, int N) {
    int t = threadIdx.x;
    int node = blockIdx.x * 16 + (t >> 4);
    int lane = t & 15;
    if (node >= N) return;
    int rs = row_start[node], re = row_end[node];
    float acc = __half2float(xs[(size_t)node * 16 + lane]);   // self-loop term

    int e0 = rs;
    for (; e0 + 16 <= re; e0 += 16) {           // full chunks: 16 loads in flight
        int idx = csr[e0 + lane];
        float v[16];
#pragma unroll
        for (int j = 0; j < 16; ++j) {
            int s = __shfl(idx, j, 16);
            v[j] = __half2float(xs[(size_t)s * 16 + lane]);
        }
#pragma unroll
        for (int j = 0; j < 16; ++j) acc += v[j];
    }
    if (e0 < re) {                              // ragged tail (1..15 edges)
        int idx = (e0 + lane < re) ? csr[e0 + lane] : 0;
        int m = re - e0;
        float v[16];
#pragma unroll
        for (int j = 0; j < 16; ++j) {
            int s = __shfl(idx, j, 16);
            v[j] = 0.0f;
            if (j < m) v[j] = __half2float(xs[(size_t)s * 16 + lane]);
        }
#pragma unroll
        for (int j = 0; j < 16; ++j) acc += v[j];
    }

    float di = dinv[node];
    float h = fmaxf(fmaf(di, acc, b1[lane]), 0.0f);
    hs[(size_t)node * 16 + lane] = __float2half_rn(h * di);
}

// u = dinv*(hs[self]+sum hs[csr]); z = u@W2+b2; s1=z.We[:64]; s2=z.We[64:]
// Round 6: u broadcast via in-group shfl (no LDS round-trip, no second
// barrier -> groups retire independently, no block-level degree imbalance).
__global__ __launch_bounds__(256) void gather2_fin2_kernel(const __half* __restrict__ hs,
                                                           const int* __restrict__ csr,
                                                           const int* __restrict__ row_start,
                                                           const int* __restrict__ row_end,
                                                           const float* __restrict__ dinv,
                                                           const float* __restrict__ W2,
                                                           const float* __restrict__ b2,
                                                           const float* __restrict__ We,
                                                           float* __restrict__ z,
                                                           float* __restrict__ s1,
                                                           float* __restrict__ s2, int N) {
    __shared__ float w2l[16 * 64];
    __shared__ float wel[128];
    __shared__ float b2l[64];
    int t = threadIdx.x;
    for (int i = t; i < 1024; i += 256) w2l[i] = W2[i];
    if (t < 128) wel[t] = We[t];
    if (t < 64) b2l[t] = b2[t];
    __syncthreads();          // only barrier: weight staging, before gather

    int g = t >> 4, lane = t & 15;
    int node = blockIdx.x * 16 + g;
    if (node >= N) return;

    int rs = row_start[node], re = row_end[node];
    float acc = __half2float(hs[(size_t)node * 16 + lane]);

    int e0 = rs;
    for (; e0 + 16 <= re; e0 += 16) {       // full chunks: 16 loads in flight
        int idx = csr[e0 + lane];
        float v[16];
#pragma unroll
        for (int j = 0; j < 16; ++j) {
            int s = __shfl(idx, j, 16);
            v[j] = __half2float(hs[(size_t)s * 16 + lane]);
        }
#pragma unroll
        for (int j = 0; j < 16; ++j) acc += v[j];
    }
    if (e0 < re) {                          // ragged tail
        int idx = (e0 + lane < re) ? csr[e0 + lane] : 0;
        int m = re - e0;
        float v[16];
#pragma unroll
        for (int j = 0; j < 16; ++j) {
            int s = __shfl(idx, j, 16);
            v[j] = 0.0f;
            if (j < m) v[j] = __half2float(hs[(size_t)s * 16 + lane]);
        }
#pragma unroll
        for (int j = 0; j < 16; ++j) acc += v[j];
    }

    float uv = acc * dinv[node];           // this lane's u[lane]

    int c0 = lane * 4;
    float z0 = b2l[c0], z1 = b2l[c0 + 1], z2 = b2l[c0 + 2], z3 = b2l[c0 + 3];
#pragma unroll
    for (int k = 0; k < 16; ++k) {
        float uk = __shfl(uv, k, 16);      // broadcast u[k] within group
        const float* wr = &w2l[k * 64 + c0];
        z0 = fmaf(uk, wr[0], z0);
        z1 = fmaf(uk, wr[1], z1);
        z2 = fmaf(uk, wr[2], z2);
        z3 = fmaf(uk, wr[3], z3);
    }
    float p1 = z0 * wel[c0] + z1 * wel[c0 + 1] + z2 * wel[c0 + 2] + z3 * wel[c0 + 3];
    float p2 = z0 * wel[64 + c0] + z1 * wel[64 + c0 + 1] + z2 * wel[64 + c0 + 2] + z3 * wel[64 + c0 + 3];
#pragma unroll
    for (int off = 1; off < 16; off <<= 1) {
        p1 += __shfl_xor(p1, off, 16);
        p2 += __shfl_xor(p2, off, 16);
    }
    ((float4*)(z + (size_t)node * 64))[lane] = make_float4(z0, z1, z2, z3);
    if (lane == 0) { s1[node] = p1; s2[node] = p2; }
}

// fused pos+neg logits; nontemporal edge-list streams (protect s1/s2 in L2)
__global__ void logits_kernel(const int* __restrict__ psrc, const int* __restrict__ pdst,
                              const int* __restrict__ nsrc, const int* __restrict__ ndst,
                              const float* __restrict__ s1, const float* __restrict__ s2,
                              const float* __restrict__ be, float* __restrict__ out,
                              int EP, int ET) {
    int e = blockIdx.x * blockDim.x + threadIdx.x;
    if (e >= ET) return;
    int s, d;
    if (e < EP) {
        s = __builtin_nontemporal_load(psrc + e);
        d = __builtin_nontemporal_load(pdst + e);
    } else {
        s = __builtin_nontemporal_load(nsrc + (e - EP));
        d = __builtin_nontemporal_load(ndst + (e - EP));
    }
    float r = s1[s] + s2[d] + be[0];
    __builtin_nontemporal_store(r, out + e);
}

extern "C" void kernel_launch(void* const* d_in, const int* in_sizes, int n_in,
                              void* d_out, int out_size, void* d_ws, size_t ws_size,
                              hipStream_t stream) {
    const float* x  = (const float*)d_in[0];
    const float* W1 = (const float*)d_in[1];
    const float* b1 = (const float*)d_in[2];
    const float* W2 = (const float*)d_in[3];
    const float* b2 = (const float*)d_in[4];
    const float* We = (const float*)d_in[5];
    const float* be = (const float*)d_in[6];
    const int* ei   = (const int*)d_in[7];
    const int* pei  = (const int*)d_in[8];
    const int* nei  = (const int*)d_in[9];

    const int N  = in_sizes[0] / 512;
    const int E  = in_sizes[7] / 2;
    const int EP = in_sizes[8] / 2;
    const int EN = in_sizes[9] / 2;
    const int NB = (N + W_BKT - 1) >> LOG_W;   // 782

    const int* src  = ei;
    const int* dst  = ei + E;
    const int* psrc = pei;
    const int* pdst = pei + EP;
    const int* nsrc = nei;
    const int* ndst = nei + EN;

    // workspace layout (4-byte units)
    int* wsp = (int*)d_ws;
    int*   bcursor   = wsp;                          // [NB_MAX]
    float* dinv      = (float*)(wsp + NB_MAX);       // [N]
    int*   row_start = (int*)(dinv + N);             // [N]
    int*   row_end   = row_start + N;                // [N]
    float* s1        = (float*)(row_end + N);        // [N]
    float* s2        = s1 + N;                       // [N]
    __half* xs       = (__half*)(s2 + N);            // [16N] halves = 8N words
    __half* hs       = xs + (size_t)16 * N;          // [16N] halves
    int*   pairs     = (int*)(hs + (size_t)16 * N);  // [NB*CAP] -> csr in place

    float* z_out = (float*)d_out;                 // [N,64]
    float* logit_out = z_out + (size_t)64 * N;    // [EP+EN]

    hipMemsetAsync(bcursor, 0, NB_MAX * sizeof(int), stream);

    int gA  = (E + EPB - 1) / EPB;       // 391
    int g16 = (N + 15) / 16;
    int g64 = (N + 63) / 64;

    scatterA_kernel<<<gA, TPB, 0, stream>>>(src, dst, bcursor, pairs, E, NB);
    bucketB_kernel<<<NB, TPB, 0, stream>>>(bcursor, pairs, dinv, row_start, row_end, N);

    gemm1_kernel<<<g64, TPB, 0, stream>>>(x, W1, dinv, xs, N);

    gather1_kernel<<<g16, TPB, 0, stream>>>(xs, pairs, row_start, row_end, dinv, b1, hs, N);
    gather2_fin2_kernel<<<g16, TPB, 0, stream>>>(hs, pairs, row_start, row_end, dinv,
                                                 W2, b2, We, z_out, s1, s2, N);

    int ET = EP + EN;
    int gL = (ET + TPB - 1) / TPB;
    logits_kernel<<<gL, TPB, 0, stream>>>(psrc, pdst, nsrc, ndst, s1, s2, be,
                                          logit_out, EP, ET);
}

// Round 3
// 479.244 us; speedup vs baseline: 1.1125x; 1.1125x over previous
//
#include <hip/hip_runtime.h>
#include <hip/hip_bf16.h>
#include <hip/hip_fp16.h>

// Pipeline (round 7 — fp16 payload, nontemporal reverted):
//   scatterA: bucket edges by dst>>7 into pairs[] (packed dl<<17|src),
//             LDS counting-sort -> wave-coalesced run writes
//   bucketB : per-bucket LDS sort -> dinv/row_start/row_end + csr (in-place)
//   xs(h16) = (x @ W1) * dinv[row]   (gemm1, K-split-4, PLAIN float4 loads)
//   gather1: hs(h16) = relu(dinv*(xs[self]+sum xs[csr]) + b1) * dinv
//   gather2: u = dinv*(hs[self]+sum hs[csr]); z = u@W2+b2; s1,s2 = z.We
//            (u broadcast via in-group shfl — no block barrier after staging)
//   logits (fused pos+neg) = s1[src] + s2[dst] + be
// Round 6 lesson (measured): __builtin_nontemporal_load on the x stream
// dropped gemm1 to 1.47 TB/s (122us, 4x slow) — nt demotes the load path on
// gfx950. Reverted everywhere. fp16 xs/hs payload kept (gathers ~30us faster,
// absmax unchanged at 4.9e-4).

constexpr int TPB = 256;
constexpr int LOG_W = 7;
constexpr int W_BKT = 128;      // nodes per bucket
constexpr int NB_MAX = 1024;    // LDS array sizing (actual NB = 782)
constexpr int CAP = 5120;       // slots/bucket (mean 4096, sigma 64 -> +16s)
constexpr int EPB = 8192;       // edges per scatterA block

__global__ __launch_bounds__(256) void scatterA_kernel(const int* __restrict__ src,
                                                       const int* __restrict__ dst,
                                                       int* __restrict__ bcursor,
                                                       int* __restrict__ pairs,
                                                       int E, int NB) {
    __shared__ int hist[NB_MAX];
    __shared__ int lstart[NB_MAX];
    __shared__ int gbase[NB_MAX];
    __shared__ int lcur[NB_MAX];
    __shared__ int csum[256];
    __shared__ int val[EPB];
    __shared__ unsigned short bkt[EPB];
    const int t = threadIdx.x;
    const int e0 = blockIdx.x * EPB;
    const int cnt = min(EPB, E - e0);

    for (int i = t; i < NB; i += 256) hist[i] = 0;
    __syncthreads();
    for (int i = t; i < cnt; i += 256) atomicAdd(&hist[dst[e0 + i] >> LOG_W], 1);
    __syncthreads();

    // exclusive scan of hist[0..NB) -> lstart (4 entries/thread + block scan)
    int loc[4], tsum = 0;
#pragma unroll
    for (int j = 0; j < 4; ++j) {
        int idx = t * 4 + j;
        int v = (idx < NB) ? hist[idx] : 0;
        loc[j] = tsum; tsum += v;
    }
    csum[t] = tsum;
    __syncthreads();
    for (int off = 1; off < 256; off <<= 1) {
        int v = (t >= off) ? csum[t - off] : 0;
        __syncthreads();
        csum[t] += v;
        __syncthreads();
    }
    int cbase = (t > 0) ? csum[t - 1] : 0;
#pragma unroll
    for (int j = 0; j < 4; ++j) {
        int idx = t * 4 + j;
        if (idx < NB) lstart[idx] = cbase + loc[j];
    }
    __syncthreads();
    // reserve global runs; init local cursors
    for (int b = t; b < NB; b += 256) {
        gbase[b] = hist[b] ? atomicAdd(&bcursor[b], hist[b]) : 0;
        lcur[b] = lstart[b];
    }
    __syncthreads();
    // counting-sort into LDS (re-read edges; coalesced, L3-hot)
    for (int i = t; i < cnt; i += 256) {
        int s = src[e0 + i], d = dst[e0 + i];
        int b = d >> LOG_W;
        int p = atomicAdd(&lcur[b], 1);
        val[p] = ((d & (W_BKT - 1)) << 17) | s;
        bkt[p] = (unsigned short)b;
    }
    __syncthreads();
    // coalesced copy-out of per-bucket runs
    for (int i = t; i < cnt; i += 256) {
        int b = bkt[i];
        int ofs = gbase[b] + (i - lstart[b]);
        if (ofs < CAP) pairs[(size_t)b * CAP + ofs] = val[i];
    }
}

// one block per bucket: counts -> dinv/row_start/row_end, LDS sort -> csr
__global__ __launch_bounds__(256) void bucketB_kernel(const int* __restrict__ bcursor,
                                                      int* __restrict__ pairs,  // in-place -> csr
                                                      float* __restrict__ dinv,
                                                      int* __restrict__ row_start,
                                                      int* __restrict__ row_end,
                                                      int N) {
    __shared__ int cnt[W_BKT];
    __shared__ int scn[W_BKT];
    __shared__ int cur[W_BKT];
    __shared__ int img[CAP];
    const int b = blockIdx.x;
    const int t = threadIdx.x;
    const int len = min(bcursor[b], CAP);
    const int n0 = b * W_BKT;
    int* p = pairs + (size_t)b * CAP;

    if (t < W_BKT) cnt[t] = 0;
    __syncthreads();
    for (int i = t; i < len; i += 256) atomicAdd(&cnt[p[i] >> 17], 1);
    __syncthreads();
    if (t < W_BKT) scn[t] = cnt[t];
    __syncthreads();
    for (int off = 1; off < W_BKT; off <<= 1) {
        int v = (t < W_BKT && t >= off) ? scn[t - off] : 0;
        __syncthreads();
        if (t < W_BKT) scn[t] += v;
        __syncthreads();
    }
    if (t < W_BKT) {
        int c = cnt[t];
        int es = scn[t] - c;          // exclusive start
        cur[t] = es;
        int n = n0 + t;
        if (n < N) {
            dinv[n] = rsqrtf((float)(c + 1));
            int rs = b * CAP + es;
            row_start[n] = rs;
            row_end[n] = rs + c;
        }
    }
    __syncthreads();
    for (int i = t; i < len; i += 256) {
        int v = p[i];
        int r = atomicAdd(&cur[v >> 17], 1);
        img[r] = v & 0x1FFFF;
    }
    __syncthreads();
    for (int i = t; i < len; i += 256) p[i] = img[i];
}

// xs = (x @ W1) * dinv[row], stored fp16.  K-split-4, plain float4 x loads.
__global__ __launch_bounds__(256) void gemm1_kernel(const float* __restrict__ x,
                                                    const float* __restrict__ W1,
                                                    const float* __restrict__ dinv,
                                                    __half* __restrict__ xs, int N) {
    __shared__ float buf[512 * 16];  // W1 during compute, reduction after
    const int t = threadIdx.x;
    {
        const float4* w4 = (const float4*)W1;
        float4* b4 = (float4*)buf;
        for (int i = t; i < 2048; i += 256) b4[i] = w4[i];
    }
    __syncthreads();

    const int r = t & 63, q = t >> 6;
    const int row = blockIdx.x * 64 + r;
    const bool valid = row < N;
    const float* xrow = x + (size_t)row * 512 + q * 128;

    float acc[16];
#pragma unroll
    for (int c = 0; c < 16; ++c) acc[c] = 0.0f;

    if (valid) {
        const int kb = q * 128;
#pragma unroll 2
        for (int k0 = 0; k0 < 128; k0 += 16) {
            const float4* xp = (const float4*)(xrow + k0);
            float4 a0 = xp[0], a1 = xp[1], a2 = xp[2], a3 = xp[3];
            float xv[16] = {a0.x, a0.y, a0.z, a0.w, a1.x, a1.y, a1.z, a1.w,
                            a2.x, a2.y, a2.z, a2.w, a3.x, a3.y, a3.z, a3.w};
#pragma unroll
            for (int kk = 0; kk < 16; ++kk) {
                const float4* wr = (const float4*)(buf + (kb + k0 + kk) * 16);
                float4 w0 = wr[0], w1 = wr[1], w2 = wr[2], w3 = wr[3];
                float xvk = xv[kk];
                acc[0]  += xvk * w0.x; acc[1]  += xvk * w0.y; acc[2]  += xvk * w0.z; acc[3]  += xvk * w0.w;
                acc[4]  += xvk * w1.x; acc[5]  += xvk * w1.y; acc[6]  += xvk * w1.z; acc[7]  += xvk * w1.w;
                acc[8]  += xvk * w2.x; acc[9]  += xvk * w2.y; acc[10] += xvk * w2.z; acc[11] += xvk * w2.w;
                acc[12] += xvk * w3.x; acc[13] += xvk * w3.y; acc[14] += xvk * w3.z; acc[15] += xvk * w3.w;
            }
        }
    }
    __syncthreads();

    float* red = buf;  // [3][64][16]
    if (q > 0) {
        float4* d0 = (float4*)(red + ((q - 1) * 64 + r) * 16);
        d0[0] = make_float4(acc[0], acc[1], acc[2], acc[3]);
        d0[1] = make_float4(acc[4], acc[5], acc[6], acc[7]);
        d0[2] = make_float4(acc[8], acc[9], acc[10], acc[11]);
        d0[3] = make_float4(acc[12], acc[13], acc[14], acc[15]);
    }
    __syncthreads();
    if (q == 0 && valid) {
#pragma unroll
        for (int p = 0; p < 3; ++p) {
            const float* sr = red + (p * 64 + r) * 16;
#pragma unroll
            for (int c = 0; c < 16; ++c) acc[c] += sr[c];
        }
        float di = dinv[row];
        __half hv[16];
#pragma unroll
        for (int c = 0; c < 16; ++c) hv[c] = __float2half_rn(acc[c] * di);
        float4* o = (float4*)(xs + (size_t)row * 16);   // 32B/row, 16B-aligned
        o[0] = *(const float4*)&hv[0];
        o[1] = *(const float4*)&hv[8];
    }
}

// hs[d] = relu(dinv[d]*(xs[d] + sum xs[csr]) + b1) * dinv[d]   (fp16 payload)
__global__ __launch_bounds__(256) void gather1_kernel(const __half* __restrict__ xs,
                                                      const int* __restrict__ csr,
                                                      const int* __restrict__ row_start,
                                                      const int* __restrict__ row_end,
                                                      const float* __restrict__ dinv,
                                                      const float* __restrict__ b1,
                                                      __half* __restrict__ hs, int N) {
    int t = threadIdx.x;
    int node = blockIdx.x * 16 + (t >> 4);
    int lane = t & 15;
    if (node >= N) return;
    int rs = row_start[node], re = row_end[node];
    float acc = __half2float(xs[(size_t)node * 16 + lane]);   // self-loop term

    int e0 = rs;
    for (; e0 + 16 <= re; e0 += 16) {           // full chunks: 16 loads in flight
        int idx = csr[e0 + lane];
        float v[16];
#pragma unroll
        for (int j = 0; j < 16; ++j) {
            int s = __shfl(idx, j, 16);
            v[j] = __half2float(xs[(size_t)s * 16 + lane]);
        }
#pragma unroll
        for (int j = 0; j < 16; ++j) acc += v[j];
    }
    if (e0 < re) {                              // ragged tail (1..15 edges)
        int idx = (e0 + lane < re) ? csr[e0 + lane] : 0;
        int m = re - e0;
        float v[16];
#pragma unroll
        for (int j = 0; j < 16; ++j) {
            int s = __shfl(idx, j, 16);
            v[j] = 0.0f;
            if (j < m) v[j] = __half2float(xs[(size_t)s * 16 + lane]);
        }
#pragma unroll
        for (int j = 0; j < 16; ++j) acc += v[j];
    }

    float di = dinv[node];
    float h = fmaxf(fmaf(di, acc, b1[lane]), 0.0f);
    hs[(size_t)node * 16 + lane] = __float2half_rn(h * di);
}

// u = dinv*(hs[self]+sum hs[csr]); z = u@W2+b2; s1=z.We[:64]; s2=z.We[64:]
// u broadcast via in-group shfl (no LDS round-trip, groups retire independently)
__global__ __launch_bounds__(256) void gather2_fin2_kernel(const __half* __restrict__ hs,
                                                           const int* __restrict__ csr,
                                                           const int* __restrict__ row_start,
                                                           const int* __restrict__ row_end,
                                                           const float* __restrict__ dinv,
                                                           const float* __restrict__ W2,
                                                           const float* __restrict__ b2,
                                                           const float* __restrict__ We,
                                                           float* __restrict__ z,
                                                           float* __restrict__ s1,
                                                           float* __restrict__ s2, int N) {
    __shared__ float w2l[16 * 64];
    __shared__ float wel[128];
    __shared__ float b2l[64];
    int t = threadIdx.x;
    for (int i = t; i < 1024; i += 256) w2l[i] = W2[i];
    if (t < 128) wel[t] = We[t];
    if (t < 64) b2l[t] = b2[t];
    __syncthreads();          // only barrier: weight staging, before gather

    int g = t >> 4, lane = t & 15;
    int node = blockIdx.x * 16 + g;
    if (node >= N) return;

    int rs = row_start[node], re = row_end[node];
    float acc = __half2float(hs[(size_t)node * 16 + lane]);

    int e0 = rs;
    for (; e0 + 16 <= re; e0 += 16) {       // full chunks: 16 loads in flight
        int idx = csr[e0 + lane];
        float v[16];
#pragma unroll
        for (int j = 0; j < 16; ++j) {
            int s = __shfl(idx, j, 16);
            v[j] = __half2float(hs[(size_t)s * 16 + lane]);
        }
#pragma unroll
        for (int j = 0; j < 16; ++j) acc += v[j];
    }
    if (e0 < re) {                          // ragged tail
        int idx = (e0 + lane < re) ? csr[e0 + lane] : 0;
        int m = re - e0;
        float v[16];
#pragma unroll
        for (int j = 0; j < 16; ++j) {
            int s = __shfl(idx, j, 16);
            v[j] = 0.0f;
            if (j < m) v[j] = __half2float(hs[(size_t)s * 16 + lane]);
        }
#pragma unroll
        for (int j = 0; j < 16; ++j) acc += v[j];
    }

    float uv = acc * dinv[node];           // this lane's u[lane]

    int c0 = lane * 4;
    float z0 = b2l[c0], z1 = b2l[c0 + 1], z2 = b2l[c0 + 2], z3 = b2l[c0 + 3];
#pragma unroll
    for (int k = 0; k < 16; ++k) {
        float uk = __shfl(uv, k, 16);      // broadcast u[k] within group
        const float* wr = &w2l[k * 64 + c0];
        z0 = fmaf(uk, wr[0], z0);
        z1 = fmaf(uk, wr[1], z1);
        z2 = fmaf(uk, wr[2], z2);
        z3 = fmaf(uk, wr[3], z3);
    }
    float p1 = z0 * wel[c0] + z1 * wel[c0 + 1] + z2 * wel[c0 + 2] + z3 * wel[c0 + 3];
    float p2 = z0 * wel[64 + c0] + z1 * wel[64 + c0 + 1] + z2 * wel[64 + c0 + 2] + z3 * wel[64 + c0 + 3];
#pragma unroll
    for (int off = 1; off < 16; off <<= 1) {
        p1 += __shfl_xor(p1, off, 16);
        p2 += __shfl_xor(p2, off, 16);
    }
    ((float4*)(z + (size_t)node * 64))[lane] = make_float4(z0, z1, z2, z3);
    if (lane == 0) { s1[node] = p1; s2[node] = p2; }
}

// fused pos+neg logits (plain loads — nt reverted)
__global__ void logits_kernel(const int* __restrict__ psrc, const int* __restrict__ pdst,
                              const int* __restrict__ nsrc, const int* __restrict__ ndst,
                              const float* __restrict__ s1, const float* __restrict__ s2,
                              const float* __restrict__ be, float* __restrict__ out,
                              int EP, int ET) {
    int e = blockIdx.x * blockDim.x + threadIdx.x;
    if (e >= ET) return;
    int s, d;
    if (e < EP) {
        s = psrc[e];
        d = pdst[e];
    } else {
        s = nsrc[e - EP];
        d = ndst[e - EP];
    }
    out[e] = s1[s] + s2[d] + be[0];
}

extern "C" void kernel_launch(void* const* d_in, const int* in_sizes, int n_in,
                              void* d_out, int out_size, void* d_ws, size_t ws_size,
                              hipStream_t stream) {
    const float* x  = (const float*)d_in[0];
    const float* W1 = (const float*)d_in[1];
    const float* b1 = (const float*)d_in[2];
    const float* W2 = (const float*)d_in[3];
    const float* b2 = (const float*)d_in[4];
    const float* We = (const float*)d_in[5];
    const float* be = (const float*)d_in[6];
    const int* ei   = (const int*)d_in[7];
    const int* pei  = (const int*)d_in[8];
    const int* nei  = (const int*)d_in[9];

    const int N  = in_sizes[0] / 512;
    const int E  = in_sizes[7] / 2;
    const int EP = in_sizes[8] / 2;
    const int EN = in_sizes[9] / 2;
    const int NB = (N + W_BKT - 1) >> LOG_W;   // 782

    const int* src  = ei;
    const int* dst  = ei + E;
    const int* psrc = pei;
    const int* pdst = pei + EP;
    const int* nsrc = nei;
    const int* ndst = nei + EN;

    // workspace layout (4-byte units)
    int* wsp = (int*)d_ws;
    int*   bcursor   = wsp;                          // [NB_MAX]
    float* dinv      = (float*)(wsp + NB_MAX);       // [N]
    int*   row_start = (int*)(dinv + N);             // [N]
    int*   row_end   = row_start + N;                // [N]
    float* s1        = (float*)(row_end + N);        // [N]
    float* s2        = s1 + N;                       // [N]
    __half* xs       = (__half*)(s2 + N);            // [16N] halves = 8N words
    __half* hs       = xs + (size_t)16 * N;          // [16N] halves
    int*   pairs     = (int*)(hs + (size_t)16 * N);  // [NB*CAP] -> csr in place

    float* z_out = (float*)d_out;                 // [N,64]
    float* logit_out = z_out + (size_t)64 * N;    // [EP+EN]

    hipMemsetAsync(bcursor, 0, NB_MAX * sizeof(int), stream);

    int gA  = (E + EPB - 1) / EPB;       // 391
    int g16 = (N + 15) / 16;
    int g64 = (N + 63) / 64;

    scatterA_kernel<<<gA, TPB, 0, stream>>>(src, dst, bcursor, pairs, E, NB);
    bucketB_kernel<<<NB, TPB, 0, stream>>>(bcursor, pairs, dinv, row_start, row_end, N);

    gemm1_kernel<<<g64, TPB, 0, stream>>>(x, W1, dinv, xs, N);

    gather1_kernel<<<g16, TPB, 0, stream>>>(xs, pairs, row_start, row_end, dinv, b1, hs, N);
    gather2_fin2_kernel<<<g16, TPB, 0, stream>>>(hs, pairs, row_start, row_end, dinv,
                                                 W2, b2, We, z_out, s1, s2, N);

    int ET = EP + EN;
    int gL = (ET + TPB - 1) / TPB;
    logits_kernel<<<gL, TPB, 0, stream>>>(psrc, pdst, nsrc, ndst, s1, s2, be,
                                          logit_out, EP, ET);
}